// Round 2
// baseline (418.911 us; speedup 1.0000x reference)
//
#include <hip/hip_runtime.h>

// Problem constants (fixed shapes from setup_inputs)
#define BATCH 2
#define HH 64
#define WW 64
#define CC 128
#define OHH 32
#define OWW 32
#define NPOOL (OHH * OWW * CC)            // 131072
#define NOUT 32
#define NIN (HH * WW * CC)                // 524288
#define WZERO ((size_t)BATCH * NIN * NOUT)  // 33554432 floats per w_zero output

// Flat offsets into d_out (floats), concatenated in return order:
// w_zero(33554432) | b_out_u_(64) | w_zero(33554432) | b_out_l_(64)
#define OFF_BU (WZERO)
#define OFF_BL (2 * WZERO + (size_t)BATCH * NOUT)

#define CHUNKS 1024                // blocks per batch element in reduce
#define PPC (NPOOL / CHUNKS)       // 128 pooled positions per block

// Custom zero-fill: hipMemsetAsync's fillBufferAligned measured 166 us with
// WRITE_SIZE = 4x the buffer (1.07 GB for a 268 MB fill). Hand-rolled
// grid-stride float4 stores write exactly 268 MB -> ~42 us at ~6.3 TB/s.
__global__ void zero_kernel(float4* __restrict__ out, size_t n4) {
    size_t tid = (size_t)blockIdx.x * blockDim.x + threadIdx.x;
    size_t stride = (size_t)gridDim.x * blockDim.x;
    const float4 z = make_float4(0.f, 0.f, 0.f, 0.f);
    for (size_t i = tid; i < n4; i += stride)
        out[i] = z;
}

// Computes b_u = maxpool2x2(u_c), b_l = maxpool2x2(l_c) into workspace
// (float4 over channel dim), and seeds the output bias slots with
// b_out_u / b_out_l (runs after the zero kernel on the same stream).
__global__ void pool_kernel(const float4* __restrict__ u_c,
                            const float4* __restrict__ l_c,
                            float4* __restrict__ bu,
                            float4* __restrict__ bl,
                            const float* __restrict__ b_out_u,
                            const float* __restrict__ b_out_l,
                            float* __restrict__ out) {
    int tid = blockIdx.x * blockDim.x + threadIdx.x;   // 65536 threads total
    int c4 = tid & 31;              // 128/4 channel quads
    int ow = (tid >> 5) & 31;
    int oh = (tid >> 10) & 31;
    int b  = tid >> 15;

    // float4-unit addressing: ((b*H + h)*W + w)*32 + c4
    int base = ((b * HH + 2 * oh) * WW + 2 * ow) * (CC / 4) + c4;
    const int colstep = CC / 4;          // +1 in w
    const int rowstep = WW * (CC / 4);   // +1 in h

    {
        float4 a0 = u_c[base];
        float4 a1 = u_c[base + colstep];
        float4 a2 = u_c[base + rowstep];
        float4 a3 = u_c[base + rowstep + colstep];
        float4 m;
        m.x = fmaxf(fmaxf(a0.x, a1.x), fmaxf(a2.x, a3.x));
        m.y = fmaxf(fmaxf(a0.y, a1.y), fmaxf(a2.y, a3.y));
        m.z = fmaxf(fmaxf(a0.z, a1.z), fmaxf(a2.z, a3.z));
        m.w = fmaxf(fmaxf(a0.w, a1.w), fmaxf(a2.w, a3.w));
        bu[tid] = m;
    }
    {
        float4 a0 = l_c[base];
        float4 a1 = l_c[base + colstep];
        float4 a2 = l_c[base + rowstep];
        float4 a3 = l_c[base + rowstep + colstep];
        float4 m;
        m.x = fmaxf(fmaxf(a0.x, a1.x), fmaxf(a2.x, a3.x));
        m.y = fmaxf(fmaxf(a0.y, a1.y), fmaxf(a2.y, a3.y));
        m.z = fmaxf(fmaxf(a0.z, a1.z), fmaxf(a2.z, a3.z));
        m.w = fmaxf(fmaxf(a0.w, a1.w), fmaxf(a2.w, a3.w));
        bl[tid] = m;
    }

    // Seed bias slots (zeroed by the preceding fill) with b_out_u / b_out_l.
    if (blockIdx.x == 0 && threadIdx.x < BATCH * NOUT) {
        out[OFF_BU + threadIdx.x] = b_out_u[threadIdx.x];
        out[OFF_BL + threadIdx.x] = b_out_l[threadIdx.x];
    }
}

// Folds backward weights into constant biases:
//   b_out_u_ += sum_p max(w_u,0)*b_u[p] + min(w_u,0)*b_l[p]
//   b_out_l_ += sum_p max(w_l,0)*b_l[p] + min(w_l,0)*b_u[p]
// Thread layout: o-quad fastest (og = t&7 -> 4 consecutive n_out cols via
// float4), pl = t>>3 strides pooled positions -> fully coalesced w reads.
// 2048 blocks (8/CU, up to 32 waves/CU) + unrolled 4-iter loop for MLP.
__global__ void reduce_kernel(const float4* __restrict__ wu,
                              const float4* __restrict__ wl,
                              const float* __restrict__ bu,
                              const float* __restrict__ bl,
                              float* __restrict__ out) {
    int b = blockIdx.x / CHUNKS;
    int chunk = blockIdx.x % CHUNKS;
    int t = threadIdx.x;
    int og = t & 7;    // which float4 of the 32 outputs
    int pl = t >> 3;   // 0..31

    float4 au = make_float4(0.f, 0.f, 0.f, 0.f);
    float4 al = make_float4(0.f, 0.f, 0.f, 0.f);

    const float* bub = bu + b * NPOOL;
    const float* blb = bl + b * NPOOL;
    int p0 = chunk * PPC;

#pragma unroll
    for (int it = 0; it < PPC / 32; ++it) {
        int p = p0 + pl + it * 32;
        float vbu = bub[p];
        float vbl = blb[p];
        size_t widx = ((size_t)b * NPOOL + p) * (NOUT / 4) + og;
        float4 u4 = wu[widx];
        float4 l4 = wl[widx];
        au.x += fmaxf(u4.x, 0.f) * vbu + fminf(u4.x, 0.f) * vbl;
        au.y += fmaxf(u4.y, 0.f) * vbu + fminf(u4.y, 0.f) * vbl;
        au.z += fmaxf(u4.z, 0.f) * vbu + fminf(u4.z, 0.f) * vbl;
        au.w += fmaxf(u4.w, 0.f) * vbu + fminf(u4.w, 0.f) * vbl;
        al.x += fmaxf(l4.x, 0.f) * vbl + fminf(l4.x, 0.f) * vbu;
        al.y += fmaxf(l4.y, 0.f) * vbl + fminf(l4.y, 0.f) * vbu;
        al.z += fmaxf(l4.z, 0.f) * vbl + fminf(l4.z, 0.f) * vbu;
        al.w += fmaxf(l4.w, 0.f) * vbl + fminf(l4.w, 0.f) * vbu;
    }

    __shared__ float4 su[256];
    __shared__ float4 sl[256];
    su[t] = au;
    sl[t] = al;
    __syncthreads();

    // Tree reduce across pl (strides are multiples of 8, preserving og)
    for (int s = 128; s >= 8; s >>= 1) {
        if (t < s) {
            float4 xu = su[t + s];
            su[t].x += xu.x; su[t].y += xu.y; su[t].z += xu.z; su[t].w += xu.w;
            float4 xl = sl[t + s];
            sl[t].x += xl.x; sl[t].y += xl.y; sl[t].z += xl.z; sl[t].w += xl.w;
        }
        __syncthreads();
    }

    if (t < 8) {
        float4 ru = su[t];
        float4 rl = sl[t];
        float* ou = out + OFF_BU + (size_t)b * NOUT + t * 4;
        float* ol = out + OFF_BL + (size_t)b * NOUT + t * 4;
        atomicAdd(&ou[0], ru.x);
        atomicAdd(&ou[1], ru.y);
        atomicAdd(&ou[2], ru.z);
        atomicAdd(&ou[3], ru.w);
        atomicAdd(&ol[0], rl.x);
        atomicAdd(&ol[1], rl.y);
        atomicAdd(&ol[2], rl.z);
        atomicAdd(&ol[3], rl.w);
    }
}

extern "C" void kernel_launch(void* const* d_in, const int* in_sizes, int n_in,
                              void* d_out, int out_size, void* d_ws, size_t ws_size,
                              hipStream_t stream) {
    // setup_inputs order: y, x_0, u_c, l_c, w_out_u, b_out_u, w_out_l, b_out_l
    const float* u_c     = (const float*)d_in[2];
    const float* l_c     = (const float*)d_in[3];
    const float* w_out_u = (const float*)d_in[4];
    const float* b_out_u = (const float*)d_in[5];
    const float* w_out_l = (const float*)d_in[6];
    const float* b_out_l = (const float*)d_in[7];
    float* out = (float*)d_out;

    float* ws_bu = (float*)d_ws;                 // BATCH*NPOOL floats (1 MB)
    float* ws_bl = ws_bu + (size_t)BATCH * NPOOL;

    // 1) Zero the entire output (the two w_zero tensors ARE the output bulk).
    //    out_size = 67,108,992 floats, divisible by 4.
    size_t n4 = (size_t)out_size / 4;
    zero_kernel<<<2048, 256, 0, stream>>>((float4*)out, n4);

    // 2) Maxpool u_c/l_c into workspace + seed bias slots.
    pool_kernel<<<256, 256, 0, stream>>>(
        (const float4*)u_c, (const float4*)l_c,
        (float4*)ws_bu, (float4*)ws_bl,
        b_out_u, b_out_l, out);

    // 3) Fold weights into biases.
    reduce_kernel<<<BATCH * CHUNKS, 256, 0, stream>>>(
        (const float4*)w_out_u, (const float4*)w_out_l,
        ws_bu, ws_bl, out);
}

// Round 4
// 367.507 us; speedup vs baseline: 1.1399x; 1.1399x over previous
//
#include <hip/hip_runtime.h>

// Problem constants (fixed shapes from setup_inputs)
#define BATCH 2
#define HH 64
#define WW 64
#define CC 128
#define OHH 32
#define OWW 32
#define NPOOL (OHH * OWW * CC)            // 131072
#define NOUT 32
#define NIN (HH * WW * CC)                // 524288
#define WZERO ((size_t)BATCH * NIN * NOUT)  // 33554432 floats per w_zero output

// Flat offsets into d_out (floats), concatenated in return order:
// w_zero(33554432) | b_out_u_(64) | w_zero(33554432) | b_out_l_(64)
#define OFF_BU (WZERO)
#define OFF_BL (2 * WZERO + (size_t)BATCH * NOUT)

#define CHUNKS 1024                // blocks per batch element in reduce
#define PPC (NPOOL / CHUNKS)       // 128 pooled positions per block

// clang-native 16B vector for __builtin_nontemporal_* (HIP_vector_type is a
// class and is rejected by the builtin).
typedef float vfloat4 __attribute__((ext_vector_type(4)));

// Grid-stride 16B zero fill of the 268 MB output. Non-temporal stores:
// the data is never re-read, don't let it thrash L2.
__global__ void zero_kernel(vfloat4* __restrict__ out, size_t n4) {
    size_t tid = (size_t)blockIdx.x * blockDim.x + threadIdx.x;
    size_t stride = (size_t)gridDim.x * blockDim.x;
    const vfloat4 z = {0.f, 0.f, 0.f, 0.f};
    for (size_t i = tid; i < n4; i += stride)
        __builtin_nontemporal_store(z, &out[i]);
}

// b_u = maxpool2x2(u_c), b_l = maxpool2x2(l_c) into workspace (float4 over C).
__global__ void pool_kernel(const float4* __restrict__ u_c,
                            const float4* __restrict__ l_c,
                            float4* __restrict__ bu,
                            float4* __restrict__ bl) {
    int tid = blockIdx.x * blockDim.x + threadIdx.x;   // 65536 threads total
    int c4 = tid & 31;              // 128/4 channel quads
    int ow = (tid >> 5) & 31;
    int oh = (tid >> 10) & 31;
    int b  = tid >> 15;

    int base = ((b * HH + 2 * oh) * WW + 2 * ow) * (CC / 4) + c4;
    const int colstep = CC / 4;          // +1 in w
    const int rowstep = WW * (CC / 4);   // +1 in h

    {
        float4 a0 = u_c[base];
        float4 a1 = u_c[base + colstep];
        float4 a2 = u_c[base + rowstep];
        float4 a3 = u_c[base + rowstep + colstep];
        float4 m;
        m.x = fmaxf(fmaxf(a0.x, a1.x), fmaxf(a2.x, a3.x));
        m.y = fmaxf(fmaxf(a0.y, a1.y), fmaxf(a2.y, a3.y));
        m.z = fmaxf(fmaxf(a0.z, a1.z), fmaxf(a2.z, a3.z));
        m.w = fmaxf(fmaxf(a0.w, a1.w), fmaxf(a2.w, a3.w));
        bu[tid] = m;
    }
    {
        float4 a0 = l_c[base];
        float4 a1 = l_c[base + colstep];
        float4 a2 = l_c[base + rowstep];
        float4 a3 = l_c[base + rowstep + colstep];
        float4 m;
        m.x = fmaxf(fmaxf(a0.x, a1.x), fmaxf(a2.x, a3.x));
        m.y = fmaxf(fmaxf(a0.y, a1.y), fmaxf(a2.y, a3.y));
        m.z = fmaxf(fmaxf(a0.z, a1.z), fmaxf(a2.z, a3.z));
        m.w = fmaxf(fmaxf(a0.w, a1.w), fmaxf(a2.w, a3.w));
        bl[tid] = m;
    }
}

// Stage 1: per-block partial fold of weights into bias contributions.
// NO atomics (R2 lesson: 1024-way same-address atomicAdd fan-in cost ~200us).
// Each block (b, chunk) writes 64 partial floats: [u0..u31 | l0..l31] at
// part[(b*CHUNKS+chunk)*64 + slot], stored as float4 by threads t<8.
__global__ void reduce_kernel(const vfloat4* __restrict__ wu,
                              const vfloat4* __restrict__ wl,
                              const float* __restrict__ bu,
                              const float* __restrict__ bl,
                              float4* __restrict__ part) {
    int b = blockIdx.x / CHUNKS;
    int chunk = blockIdx.x % CHUNKS;
    int t = threadIdx.x;
    int og = t & 7;    // which float4 of the 32 outputs
    int pl = t >> 3;   // 0..31

    float4 au = make_float4(0.f, 0.f, 0.f, 0.f);
    float4 al = make_float4(0.f, 0.f, 0.f, 0.f);

    const float* bub = bu + b * NPOOL;
    const float* blb = bl + b * NPOOL;
    int p0 = chunk * PPC;

#pragma unroll
    for (int it = 0; it < PPC / 32; ++it) {
        int p = p0 + pl + it * 32;
        float vbu = bub[p];
        float vbl = blb[p];
        size_t widx = ((size_t)b * NPOOL + p) * (NOUT / 4) + og;
        vfloat4 u4 = __builtin_nontemporal_load(&wu[widx]);
        vfloat4 l4 = __builtin_nontemporal_load(&wl[widx]);
        au.x += fmaxf(u4.x, 0.f) * vbu + fminf(u4.x, 0.f) * vbl;
        au.y += fmaxf(u4.y, 0.f) * vbu + fminf(u4.y, 0.f) * vbl;
        au.z += fmaxf(u4.z, 0.f) * vbu + fminf(u4.z, 0.f) * vbl;
        au.w += fmaxf(u4.w, 0.f) * vbu + fminf(u4.w, 0.f) * vbl;
        al.x += fmaxf(l4.x, 0.f) * vbl + fminf(l4.x, 0.f) * vbu;
        al.y += fmaxf(l4.y, 0.f) * vbl + fminf(l4.y, 0.f) * vbu;
        al.z += fmaxf(l4.z, 0.f) * vbl + fminf(l4.z, 0.f) * vbu;
        al.w += fmaxf(l4.w, 0.f) * vbl + fminf(l4.w, 0.f) * vbu;
    }

    __shared__ float4 su[256];
    __shared__ float4 sl[256];
    su[t] = au;
    sl[t] = al;
    __syncthreads();

    // Tree reduce across pl (strides are multiples of 8, preserving og)
    for (int s = 128; s >= 8; s >>= 1) {
        if (t < s) {
            float4 xu = su[t + s];
            su[t].x += xu.x; su[t].y += xu.y; su[t].z += xu.z; su[t].w += xu.w;
            float4 xl = sl[t + s];
            sl[t].x += xl.x; sl[t].y += xl.y; sl[t].z += xl.z; sl[t].w += xl.w;
        }
        __syncthreads();
    }

    if (t < 8) {
        // float4 units: block row = (b*CHUNKS+chunk)*16; u at +t, l at +8+t
        size_t row = ((size_t)b * CHUNKS + chunk) * 16;
        part[row + t] = su[t];
        part[row + 8 + t] = sl[t];
    }
}

// Stage 2: sum 1024 partials per output scalar and add the input bias.
// 128 threads: j -> (b = j>>6, slot = j&63); slot<32 -> u output, else l.
// Reads 512 KB (L2-resident, just written). Writes the 128 bias floats.
__global__ void final_kernel(const float* __restrict__ part,
                             const float* __restrict__ b_out_u,
                             const float* __restrict__ b_out_l,
                             float* __restrict__ out) {
    int j = threadIdx.x;           // 0..127
    int b = j >> 6;
    int slot = j & 63;

    float acc = 0.f;
    const float* p = part + (size_t)b * CHUNKS * 64 + slot;
    for (int c = 0; c < CHUNKS; ++c)
        acc += p[(size_t)c * 64];

    if (slot < 32) {
        out[OFF_BU + b * NOUT + slot] = acc + b_out_u[b * NOUT + slot];
    } else {
        int o = slot - 32;
        out[OFF_BL + b * NOUT + o] = acc + b_out_l[b * NOUT + o];
    }
}

extern "C" void kernel_launch(void* const* d_in, const int* in_sizes, int n_in,
                              void* d_out, int out_size, void* d_ws, size_t ws_size,
                              hipStream_t stream) {
    // setup_inputs order: y, x_0, u_c, l_c, w_out_u, b_out_u, w_out_l, b_out_l
    const float* u_c     = (const float*)d_in[2];
    const float* l_c     = (const float*)d_in[3];
    const float* w_out_u = (const float*)d_in[4];
    const float* b_out_u = (const float*)d_in[5];
    const float* w_out_l = (const float*)d_in[6];
    const float* b_out_l = (const float*)d_in[7];
    float* out = (float*)d_out;

    float* ws_bu = (float*)d_ws;                       // BATCH*NPOOL floats (1 MB)
    float* ws_bl = ws_bu + (size_t)BATCH * NPOOL;      // 1 MB
    float* ws_part = ws_bl + (size_t)BATCH * NPOOL;    // 2*CHUNKS*64 floats (512 KB)

    // 1) Zero the entire output (the two w_zero tensors ARE the output bulk).
    size_t n4 = (size_t)out_size / 4;   // 16,777,248 float4s
    zero_kernel<<<4096, 256, 0, stream>>>((vfloat4*)out, n4);

    // 2) Maxpool u_c/l_c into workspace.
    pool_kernel<<<256, 256, 0, stream>>>(
        (const float4*)u_c, (const float4*)l_c,
        (float4*)ws_bu, (float4*)ws_bl);

    // 3) Stage-1 fold: per-block partials, no atomics.
    reduce_kernel<<<BATCH * CHUNKS, 256, 0, stream>>>(
        (const vfloat4*)w_out_u, (const vfloat4*)w_out_l,
        ws_bu, ws_bl, (float4*)ws_part);

    // 4) Stage-2: final sum + bias into the output bias slots.
    final_kernel<<<1, 128, 0, stream>>>(ws_part, b_out_u, b_out_l, out);
}

// Round 5
// 359.516 us; speedup vs baseline: 1.1652x; 1.0222x over previous
//
#include <hip/hip_runtime.h>

// Problem constants (fixed shapes from setup_inputs)
#define BATCH 2
#define HH 64
#define WW 64
#define CC 128
#define OHH 32
#define OWW 32
#define NPOOL (OHH * OWW * CC)            // 131072
#define NOUT 32
#define NIN (HH * WW * CC)                // 524288
#define WZERO ((size_t)BATCH * NIN * NOUT)  // 33554432 floats per w_zero output

// Flat offsets into d_out (floats), concatenated in return order:
// w_zero(33554432) | b_out_u_(64) | w_zero(33554432) | b_out_l_(64)
#define OFF_BU (WZERO)
#define OFF_BL (2 * WZERO + (size_t)BATCH * NOUT)

#define CHUNKS 1024                 // reduce blocks per batch element
#define PPC (NPOOL / CHUNKS)        // 128 pooled positions per block (= all C at one oh,ow)
#define RBLOCKS (BATCH * CHUNKS)    // 2048
#define ZBLOCKS 4096                // zero-fill blocks
#define NTHREADS 256

// clang-native 16B vector for __builtin_nontemporal_* (HIP_vector_type is a
// class and is rejected by the builtin).
typedef float vfloat4 __attribute__((ext_vector_type(4)));

// One heterogeneous kernel: blocks [0, RBLOCKS) do fused pool+fold (read-bound,
// 36 KB each), blocks [RBLOCKS, RBLOCKS+ZBLOCKS) zero-fill d_out (write-bound,
// 64 KB each). Running them in one dispatch lets the read stream and write
// stream share HBM concurrently instead of serializing across launches.
__global__ void __launch_bounds__(NTHREADS)
fused_kernel(const float* __restrict__ u_c,
             const float* __restrict__ l_c,
             const vfloat4* __restrict__ wu,
             const vfloat4* __restrict__ wl,
             vfloat4* __restrict__ outz, size_t n4,
             float4* __restrict__ part) {
    int bid = blockIdx.x;
    int t = threadIdx.x;

    if (bid >= RBLOCKS) {
        // ---- zero-fill portion: grid-stride over ZBLOCKS*256 threads ----
        int zb = bid - RBLOCKS;
        size_t idx = (size_t)zb * NTHREADS + t;
        const size_t stride = (size_t)ZBLOCKS * NTHREADS;  // 1,048,576
        const vfloat4 z = {0.f, 0.f, 0.f, 0.f};
        // n4 = 16,777,248 = 16*stride + 32 -> 16 full steps + 32-elem tail
        for (size_t i = idx; i < n4; i += stride)
            __builtin_nontemporal_store(z, &outz[i]);
        return;
    }

    // ---- fused pool + fold portion ----
    int rb = bid;                 // 0..2047
    int b = rb >> 10;             // / CHUNKS
    int chunk = rb & (CHUNKS - 1);
    int oh = chunk >> 5;
    int ow = chunk & 31;

    // Pool: positions p0..p0+127 are channels 0..127 at this (b,oh,ow).
    // threads 0..127 pool u_c, threads 128..255 pool l_c -> LDS.
    __shared__ float s_bu[CC];
    __shared__ float s_bl[CC];
    {
        int base = ((b * HH + 2 * oh) * WW + 2 * ow) * CC;
        if (t < CC) {
            int c = t;
            float a0 = u_c[base + c];
            float a1 = u_c[base + CC + c];
            float a2 = u_c[base + WW * CC + c];
            float a3 = u_c[base + WW * CC + CC + c];
            s_bu[c] = fmaxf(fmaxf(a0, a1), fmaxf(a2, a3));
        } else {
            int c = t - CC;
            float a0 = l_c[base + c];
            float a1 = l_c[base + CC + c];
            float a2 = l_c[base + WW * CC + c];
            float a3 = l_c[base + WW * CC + CC + c];
            s_bl[c] = fmaxf(fmaxf(a0, a1), fmaxf(a2, a3));
        }
    }
    __syncthreads();

    int og = t & 7;    // which float4 of the 32 outputs
    int pl = t >> 3;   // 0..31

    float4 au = make_float4(0.f, 0.f, 0.f, 0.f);
    float4 al = make_float4(0.f, 0.f, 0.f, 0.f);
    int p0 = chunk * PPC;

#pragma unroll
    for (int it = 0; it < PPC / 32; ++it) {
        int c = pl + it * 32;
        float vbu = s_bu[c];   // 8-lane broadcast + 8 banks -> conflict-free
        float vbl = s_bl[c];
        size_t widx = ((size_t)b * NPOOL + p0 + c) * (NOUT / 4) + og;
        vfloat4 u4 = __builtin_nontemporal_load(&wu[widx]);
        vfloat4 l4 = __builtin_nontemporal_load(&wl[widx]);
        au.x += fmaxf(u4.x, 0.f) * vbu + fminf(u4.x, 0.f) * vbl;
        au.y += fmaxf(u4.y, 0.f) * vbu + fminf(u4.y, 0.f) * vbl;
        au.z += fmaxf(u4.z, 0.f) * vbu + fminf(u4.z, 0.f) * vbl;
        au.w += fmaxf(u4.w, 0.f) * vbu + fminf(u4.w, 0.f) * vbl;
        al.x += fmaxf(l4.x, 0.f) * vbl + fminf(l4.x, 0.f) * vbu;
        al.y += fmaxf(l4.y, 0.f) * vbl + fminf(l4.y, 0.f) * vbu;
        al.z += fmaxf(l4.z, 0.f) * vbl + fminf(l4.z, 0.f) * vbu;
        al.w += fmaxf(l4.w, 0.f) * vbl + fminf(l4.w, 0.f) * vbu;
    }

    __shared__ float4 su[NTHREADS];
    __shared__ float4 sl[NTHREADS];
    su[t] = au;
    sl[t] = al;
    __syncthreads();

    // Tree reduce across pl (strides are multiples of 8, preserving og)
    for (int s = 128; s >= 8; s >>= 1) {
        if (t < s) {
            float4 xu = su[t + s];
            su[t].x += xu.x; su[t].y += xu.y; su[t].z += xu.z; su[t].w += xu.w;
            float4 xl = sl[t + s];
            sl[t].x += xl.x; sl[t].y += xl.y; sl[t].z += xl.z; sl[t].w += xl.w;
        }
        __syncthreads();
    }

    if (t < 8) {
        // float4 units: block row = rb*16; u at +t, l at +8+t
        size_t row = (size_t)rb * 16;
        part[row + t] = su[t];
        part[row + 8 + t] = sl[t];
    }
}

// Stage 2: sum 1024 partials per output scalar and add the input bias.
// 128 threads: j -> (b = j>>6, slot = j&63); slot<32 -> u output, else l.
// Reads 512 KB (L2-resident, just written). Writes the 128 bias floats.
__global__ void final_kernel(const float* __restrict__ part,
                             const float* __restrict__ b_out_u,
                             const float* __restrict__ b_out_l,
                             float* __restrict__ out) {
    int j = threadIdx.x;           // 0..127
    int b = j >> 6;
    int slot = j & 63;

    float acc = 0.f;
    const float* p = part + (size_t)b * CHUNKS * 64 + slot;
    for (int c = 0; c < CHUNKS; ++c)
        acc += p[(size_t)c * 64];

    if (slot < 32) {
        out[OFF_BU + b * NOUT + slot] = acc + b_out_u[b * NOUT + slot];
    } else {
        int o = slot - 32;
        out[OFF_BL + b * NOUT + o] = acc + b_out_l[b * NOUT + o];
    }
}

extern "C" void kernel_launch(void* const* d_in, const int* in_sizes, int n_in,
                              void* d_out, int out_size, void* d_ws, size_t ws_size,
                              hipStream_t stream) {
    // setup_inputs order: y, x_0, u_c, l_c, w_out_u, b_out_u, w_out_l, b_out_l
    const float* u_c     = (const float*)d_in[2];
    const float* l_c     = (const float*)d_in[3];
    const float* w_out_u = (const float*)d_in[4];
    const float* b_out_u = (const float*)d_in[5];
    const float* w_out_l = (const float*)d_in[6];
    const float* b_out_l = (const float*)d_in[7];
    float* out = (float*)d_out;

    float* ws_part = (float*)d_ws;   // RBLOCKS*64 floats (512 KB)

    size_t n4 = (size_t)out_size / 4;   // 16,777,248 float4s

    // 1) Zero + pool + fold, one dispatch (read & write streams overlap).
    fused_kernel<<<RBLOCKS + ZBLOCKS, NTHREADS, 0, stream>>>(
        u_c, l_c,
        (const vfloat4*)w_out_u, (const vfloat4*)w_out_l,
        (vfloat4*)out, n4, (float4*)ws_part);

    // 2) Final sum + bias into the output bias slots.
    final_kernel<<<1, 128, 0, stream>>>(ws_part, b_out_u, b_out_l, out);
}